// Round 2
// baseline (1303.996 us; speedup 1.0000x reference)
//
#include <hip/hip_runtime.h>

// Problem constants (fixed by reference setup_inputs)
constexpr int Cc   = 3;
constexpr int Hc   = 160;
constexpr int Wc   = 160;
constexpr int Hoc  = 158;
constexpr int Woc  = 158;
constexpr int Lc   = Hoc * Woc;    // 24964
constexpr int Ntot = 4 * Lc;       // 99856
constexpr int NCH  = 8;
constexpr int MDd  = 54;           // 2 * C * 3 * 3

// Compare-exchange sorting (key, pay) pairs DESCENDING by float key, payload
// follows. Plain C — expected codegen: v_cmp_lt_f32 + v_max_f32 + v_min_f32 +
// 2x v_cndmask_b32 (5 instrs, one dependency level).
//
// WHY NO INLINE ASM: round-1 counters showed VGPR_Count=64 with 3-waves/SIMD
// occupancy => the allocator homed the 108-entry sort array in AGPRs and the
// asm's "v" constraints forced a cross-file copy pair around every CE (~1.85x
// VALU instruction inflation: measured ~4800 instrs/thread vs ~2600 in
// source). The asm made arch-VGPR pressure look transient, so the allocator
// kept AGPR homes. Plain C lets it either home the array in arch VGPRs or use
// AGPR-direct VALU ops — both eliminate the shuttles.
//
// Ties (bit-equal keys): max/min don't swap, payload selects don't swap —
// consistent; equal keys carry equal output values (harness passes with a tie
// rule different from the reference already).
__device__ __forceinline__ void ce(float &ka, float &pa, float &kb, float &pb) {
    const bool sw = ka < kb;          // swap iff ka < kb (descending sort)
    const float hi = fmaxf(ka, kb);
    const float lo = fminf(ka, kb);
    const float npa = sw ? pb : pa;
    const float npb = sw ? pa : pb;
    ka = hi; kb = lo; pa = npa; pb = npb;
}

// __launch_bounds__(256, 3): min 3 waves/EU -> unified register budget 168.
// Live pressure ~135 (108-entry sort array + temps) fits. Verified round 1:
// occupancy went 26% -> 34% (2 -> 3 waves/SIMD).
__global__ __launch_bounds__(256, 3) void wos_kernel(
    const float* __restrict__ x, const float* __restrict__ weight,
    const float* __restrict__ bias, const float* __restrict__ mask,
    float* __restrict__ out)
{
    const int lane = threadIdx.x & 63;
    const int wave = threadIdx.x >> 6;
    const int grp  = blockIdx.x >> 1;
    // nc is wave-uniform: assert it so weight/mask/bias reads become scalar loads.
    const int nc   = __builtin_amdgcn_readfirstlane(((blockIdx.x & 1) << 2) | wave);
    const int n    = grp * 64 + lane;
    if (n >= Ntot) return;

    const int b  = n / Lc;
    const int l  = n - b * Lc;
    const int ho = l / Woc;
    const int wo = l - ho * Woc;

    const float* xb = x + (b * Cc) * (Hc * Wc);
    const float* mk = mask + nc * MDd;      // wave-uniform -> scalar loads
    const float* wr = weight + nc * MDd;    // wave-uniform -> scalar loads
    const float  bi = bias[nc];

    // key = mx value itself (raw fp32, sorted descending). pay = weight
    // (sorted alongside for the exact sequential cumsum).
    // mk[27+d] - v  ==  (-v) + mk[27+d] bit-exactly (IEEE a-b == a+(-b)).
    float key[MDd], pay[MDd];
    #pragma unroll
    for (int c = 0; c < 3; ++c) {
        #pragma unroll
        for (int r = 0; r < 3; ++r) {
            #pragma unroll
            for (int s = 0; s < 3; ++s) {
                const int d = c * 9 + r * 3 + s;
                const float v = xb[(c * Hc + ho + r) * Wc + wo + s];
                key[d]      = v + mk[d];
                key[27 + d] = mk[27 + d] - v;
                pay[d]      = wr[d];
                pay[27 + d] = wr[27 + d];
            }
        }
    }

    // Batcher odd-even mergesort for n=64, pruned to wires < 54 (monotone
    // network; pruned wires are implicit -inf pads under the descending
    // comparator, so dropping their CEs is a static no-op). Network structure
    // identical to the correctness-proven previous rounds.
    #pragma unroll
    for (int p = 1; p < 64; p <<= 1) {
        #pragma unroll
        for (int k = p; k >= 1; k >>= 1) {
            #pragma unroll
            for (int j = k % p; j + k < 64; j += 2 * k) {
                #pragma unroll
                for (int i = 0; i < k; ++i) {
                    const int lo = i + j;
                    const int hi = i + j + k;
                    if (hi < MDd && (lo / (2 * p) == hi / (2 * p))) {
                        ce(key[lo], pay[lo], key[hi], pay[hi]);
                    }
                }
            }
        }
    }

    // Sequential fp32 cumsum of weights in sorted (descending-mx) order —
    // bit-matches the reference (same summation order). Track the value of the
    // last rank whose cumulative weight <= bias; default (clip-to-0) is rank 0.
    float acc = 0.0f;
    float sel = key[0];
    #pragma unroll
    for (int r = 0; r < MDd; ++r) {
        acc += pay[r];
        sel = (acc <= bi) ? key[r] : sel;
    }

    out[n * NCH + nc] = sel;
}

extern "C" void kernel_launch(void* const* d_in, const int* in_sizes, int n_in,
                              void* d_out, int out_size, void* d_ws, size_t ws_size,
                              hipStream_t stream) {
    const float* x      = (const float*)d_in[0];
    const float* weight = (const float*)d_in[1];
    const float* bias   = (const float*)d_in[2];
    const float* mask   = (const float*)d_in[3];
    float* out = (float*)d_out;

    const int ngrp = (Ntot + 63) / 64;      // 1561
    dim3 grid(ngrp * 2);                    // x2 blocks: 8 nc / 4 waves
    wos_kernel<<<grid, 256, 0, stream>>>(x, weight, bias, mask, out);
}

// Round 3
// 111.946 us; speedup vs baseline: 11.6484x; 11.6484x over previous
//
#include <hip/hip_runtime.h>

// Problem constants (fixed by reference setup_inputs)
constexpr int Cc   = 3;
constexpr int Hc   = 160;
constexpr int Wc   = 160;
constexpr int Hoc  = 158;
constexpr int Woc  = 158;
constexpr int Lc   = Hoc * Woc;    // 24964
constexpr int Ntot = 4 * Lc;       // 99856
constexpr int NCH  = 8;
constexpr int MDd  = 54;           // 2 * C * 3 * 3

// Compare-exchange sorting (key, pay) pairs DESCENDING by float key, payload
// follows. 5 instructions, one dependency level (cmp -> cndmask, bridged by
// the independent max/min).
//
// MUST STAY INLINE ASM. Round-2 measured: the plain-C equivalent let the
// scheduler inflate live ranges past the register budget and spill the sort
// arrays to SCRATCH (WRITE_SIZE 6 MB -> 4.5 GB, VALUBusy 82% -> 5%, 22x
// slower). The asm acts as a scheduling fence that keeps peak pressure at
// ~the array size.
//
// Ties (bit-equal keys) don't swap; equal keys carry equal output values, so
// tie order is inconsequential (harness passes with a tie rule different from
// the reference).
__device__ __forceinline__ void ce(float &ka, float &pa, float &kb, float &pb) {
    float nka, nkb, npa, npb;
    asm("v_cmp_lt_f32 vcc, %4, %5\n\t"     // swap iff ka < kb (descending)
        "v_max_f32 %0, %4, %5\n\t"          // new ka = max
        "v_min_f32 %1, %4, %5\n\t"          // new kb = min
        "v_cndmask_b32 %2, %6, %7, vcc\n\t" // new pa = swap ? pb : pa
        "v_cndmask_b32 %3, %7, %6, vcc"     // new pb = swap ? pa : pb
        : "=&v"(nka), "=&v"(nkb), "=&v"(npa), "=v"(npb)
        : "v"(ka), "v"(kb), "v"(pa), "v"(pb)
        : "vcc");
    ka = nka; kb = nkb; pa = npa; pb = npb;
}

// __launch_bounds__(256, 2): unified register budget 256/wave — the full arch
// VGPR file. Round-1 counters (VGPR_Count=64 at a 168-reg budget, ~1.85x VALU
// instruction inflation) showed the allocator split 64 arch + 104 AGPR and
// paid v_accvgpr shuttles around every CE's "v"-constrained operands. With a
// 256-reg budget the ~135 live values (108-entry sort array + temps) fit
// entirely in ARCH VGPRs -> no AGPR homes, no shuttles. Occupancy 3 -> 2
// waves/SIMD is the price; the instruction stream shrinks ~44%, which wins.
__global__ __launch_bounds__(256, 2) void wos_kernel(
    const float* __restrict__ x, const float* __restrict__ weight,
    const float* __restrict__ bias, const float* __restrict__ mask,
    float* __restrict__ out)
{
    const int lane = threadIdx.x & 63;
    const int wave = threadIdx.x >> 6;
    const int grp  = blockIdx.x >> 1;
    // nc is wave-uniform: assert it so weight/mask/bias reads become scalar loads.
    const int nc   = __builtin_amdgcn_readfirstlane(((blockIdx.x & 1) << 2) | wave);
    const int n    = grp * 64 + lane;
    if (n >= Ntot) return;

    const int b  = n / Lc;
    const int l  = n - b * Lc;
    const int ho = l / Woc;
    const int wo = l - ho * Woc;

    const float* xb = x + (b * Cc) * (Hc * Wc);
    const float* mk = mask + nc * MDd;      // wave-uniform -> scalar loads
    const float* wr = weight + nc * MDd;    // wave-uniform -> scalar loads
    const float  bi = bias[nc];

    // key = mx value itself (raw fp32, sorted descending). pay = weight
    // (sorted alongside for the exact sequential cumsum).
    // mk[27+d] - v  ==  (-v) + mk[27+d] bit-exactly (IEEE a-b == a+(-b)).
    float key[MDd], pay[MDd];
    #pragma unroll
    for (int c = 0; c < 3; ++c) {
        #pragma unroll
        for (int r = 0; r < 3; ++r) {
            #pragma unroll
            for (int s = 0; s < 3; ++s) {
                const int d = c * 9 + r * 3 + s;
                const float v = xb[(c * Hc + ho + r) * Wc + wo + s];
                key[d]      = v + mk[d];
                key[27 + d] = mk[27 + d] - v;
                pay[d]      = wr[d];
                pay[27 + d] = wr[27 + d];
            }
        }
    }

    // Batcher odd-even mergesort for n=64, pruned to wires < 54 (monotone
    // network; pruned wires are implicit -inf pads under the descending
    // comparator, so dropping their CEs is a static no-op). Network structure
    // identical to the correctness-proven previous rounds.
    #pragma unroll
    for (int p = 1; p < 64; p <<= 1) {
        #pragma unroll
        for (int k = p; k >= 1; k >>= 1) {
            #pragma unroll
            for (int j = k % p; j + k < 64; j += 2 * k) {
                #pragma unroll
                for (int i = 0; i < k; ++i) {
                    const int lo = i + j;
                    const int hi = i + j + k;
                    if (hi < MDd && (lo / (2 * p) == hi / (2 * p))) {
                        ce(key[lo], pay[lo], key[hi], pay[hi]);
                    }
                }
            }
        }
    }

    // Sequential fp32 cumsum of weights in sorted (descending-mx) order —
    // bit-matches the reference (same summation order). Track the value of the
    // last rank whose cumulative weight <= bias; default (clip-to-0) is rank 0.
    float acc = 0.0f;
    float sel = key[0];
    #pragma unroll
    for (int r = 0; r < MDd; ++r) {
        acc += pay[r];
        sel = (acc <= bi) ? key[r] : sel;
    }

    out[n * NCH + nc] = sel;
}

extern "C" void kernel_launch(void* const* d_in, const int* in_sizes, int n_in,
                              void* d_out, int out_size, void* d_ws, size_t ws_size,
                              hipStream_t stream) {
    const float* x      = (const float*)d_in[0];
    const float* weight = (const float*)d_in[1];
    const float* bias   = (const float*)d_in[2];
    const float* mask   = (const float*)d_in[3];
    float* out = (float*)d_out;

    const int ngrp = (Ntot + 63) / 64;      // 1561
    dim3 grid(ngrp * 2);                    // x2 blocks: 8 nc / 4 waves
    wos_kernel<<<grid, 256, 0, stream>>>(x, weight, bias, mask, out);
}

// Round 4
// 109.251 us; speedup vs baseline: 11.9358x; 1.0247x over previous
//
#include <hip/hip_runtime.h>
#include <array>

// Problem constants (fixed by reference setup_inputs)
constexpr int Cc   = 3;
constexpr int Hc   = 160;
constexpr int Wc   = 160;
constexpr int Hoc  = 158;
constexpr int Woc  = 158;
constexpr int Lc   = Hoc * Woc;    // 24964
constexpr int Ntot = 4 * Lc;       // 99856
constexpr int NCH  = 8;
constexpr int MDd  = 54;           // 2 * C * 3 * 3

// ---------------------------------------------------------------------------
// Batcher odd-even mergesort network for n=64, pruned to wires < 54, flattened
// at compile time into a CE list. Identical structure to the loop-nest used in
// all previous (correctness-proven) rounds; flattening lets us place
// sched_barrier fences every FENCE_EVERY comparators.
// ---------------------------------------------------------------------------
struct CEpair { unsigned char lo, hi; };

constexpr int count_ces() {
    int cnt = 0;
    for (int p = 1; p < 64; p <<= 1)
        for (int k = p; k >= 1; k >>= 1)
            for (int j = k % p; j + k < 64; j += 2 * k)
                for (int i = 0; i < k; ++i) {
                    const int lo = i + j, hi = i + j + k;
                    if (hi < MDd && (lo / (2 * p) == hi / (2 * p))) ++cnt;
                }
    return cnt;
}
constexpr int NCE = count_ces();

constexpr std::array<CEpair, NCE> make_net() {
    std::array<CEpair, NCE> a{};
    int cnt = 0;
    for (int p = 1; p < 64; p <<= 1)
        for (int k = p; k >= 1; k >>= 1)
            for (int j = k % p; j + k < 64; j += 2 * k)
                for (int i = 0; i < k; ++i) {
                    const int lo = i + j, hi = i + j + k;
                    if (hi < MDd && (lo / (2 * p) == hi / (2 * p))) {
                        a[cnt].lo = (unsigned char)lo;
                        a[cnt].hi = (unsigned char)hi;
                        ++cnt;
                    }
                }
    return a;
}
constexpr auto NET = make_net();

// Compare-exchange sorting (key, pay) pairs DESCENDING by float key, payload
// follows. 5 instructions, one dependency level (cmp -> cndmask, bridged by
// the independent max/min).
//
// MUST STAY INLINE ASM: round 2 measured the plain-C equivalent spilling the
// sort arrays to SCRATCH (WRITE_SIZE 6 MB -> 4.5 GB, 22x slower).
// Ties (bit-equal keys) don't swap; equal keys carry equal values.
__device__ __forceinline__ void ce(float &ka, float &pa, float &kb, float &pb) {
    float nka, nkb, npa, npb;
    asm("v_cmp_lt_f32 vcc, %4, %5\n\t"     // swap iff ka < kb (descending)
        "v_max_f32 %0, %4, %5\n\t"          // new ka = max
        "v_min_f32 %1, %4, %5\n\t"          // new kb = min
        "v_cndmask_b32 %2, %6, %7, vcc\n\t" // new pa = swap ? pb : pa
        "v_cndmask_b32 %3, %7, %6, vcc"     // new pb = swap ? pa : pb
        : "=&v"(nka), "=&v"(nkb), "=&v"(npa), "=v"(npb)
        : "v"(ka), "v"(kb), "v"(pa), "v"(pb)
        : "vcc");
    ka = nka; kb = nkb; pa = npa; pb = npb;
}

// THEORY OF THIS ROUND (after rounds 1/3 falsified the budget theory):
// the pre-RA scheduler interleaves CEs across network stages, inflating live
// ranges past any budget; the allocator then spills the overflow to AGPRs
// (arch VGPR_Count pinned at 64-68 in EVERY round regardless of
// launch_bounds) and every "v"-constrained CE pays v_accvgpr shuttles
// (~4,800 measured instrs/thread vs ~2,600 in source). Fix: sched_barrier(0)
// every 8 CEs clamps peak pressure to ~108 array + 32 in-flight = ~140 regs,
// which fits the 168-reg budget of (256,3) -> 3 waves/SIMD AND no AGPR homes.
constexpr int FENCE_EVERY = 8;

__global__ __launch_bounds__(256, 3) void wos_kernel(
    const float* __restrict__ x, const float* __restrict__ weight,
    const float* __restrict__ bias, const float* __restrict__ mask,
    float* __restrict__ out)
{
    const int lane = threadIdx.x & 63;
    const int wave = threadIdx.x >> 6;
    const int grp  = blockIdx.x >> 1;
    // nc is wave-uniform: assert it so weight/mask/bias reads become scalar loads.
    const int nc   = __builtin_amdgcn_readfirstlane(((blockIdx.x & 1) << 2) | wave);
    const int n    = grp * 64 + lane;
    if (n >= Ntot) return;

    const int b  = n / Lc;
    const int l  = n - b * Lc;
    const int ho = l / Woc;
    const int wo = l - ho * Woc;

    const float* xb = x + (b * Cc) * (Hc * Wc);
    const float* mk = mask + nc * MDd;      // wave-uniform -> scalar loads
    const float* wr = weight + nc * MDd;    // wave-uniform -> scalar loads
    const float  bi = bias[nc];

    // key = mx value itself (raw fp32, sorted descending). pay = weight
    // (sorted alongside for the exact sequential cumsum).
    // mk[27+d] - v  ==  (-v) + mk[27+d] bit-exactly (IEEE a-b == a+(-b)).
    float key[MDd], pay[MDd];
    #pragma unroll
    for (int c = 0; c < 3; ++c) {
        #pragma unroll
        for (int r = 0; r < 3; ++r) {
            #pragma unroll
            for (int s = 0; s < 3; ++s) {
                const int d = c * 9 + r * 3 + s;
                const float v = xb[(c * Hc + ho + r) * Wc + wo + s];
                key[d]      = v + mk[d];
                key[27 + d] = mk[27 + d] - v;
                pay[d]      = wr[d];
                pay[27 + d] = wr[27 + d];
            }
        }
    }
    __builtin_amdgcn_sched_barrier(0);   // build may not bleed into the sort

    // Flattened sorting network with pressure fences. After full unroll every
    // NET[ci] index is a compile-time constant (arrays stay in registers).
    #pragma unroll
    for (int ci = 0; ci < NCE; ++ci) {
        ce(key[NET[ci].lo], pay[NET[ci].lo], key[NET[ci].hi], pay[NET[ci].hi]);
        if (ci % FENCE_EVERY == FENCE_EVERY - 1)
            __builtin_amdgcn_sched_barrier(0);
    }
    __builtin_amdgcn_sched_barrier(0);   // sort may not bleed into the cumsum

    // Sequential fp32 cumsum of weights in sorted (descending-mx) order —
    // bit-matches the reference (same summation order). Track the value of the
    // last rank whose cumulative weight <= bias; default (clip-to-0) is rank 0.
    float acc = 0.0f;
    float sel = key[0];
    #pragma unroll
    for (int r = 0; r < MDd; ++r) {
        acc += pay[r];
        sel = (acc <= bi) ? key[r] : sel;
    }

    out[n * NCH + nc] = sel;
}

extern "C" void kernel_launch(void* const* d_in, const int* in_sizes, int n_in,
                              void* d_out, int out_size, void* d_ws, size_t ws_size,
                              hipStream_t stream) {
    const float* x      = (const float*)d_in[0];
    const float* weight = (const float*)d_in[1];
    const float* bias   = (const float*)d_in[2];
    const float* mask   = (const float*)d_in[3];
    float* out = (float*)d_out;

    const int ngrp = (Ntot + 63) / 64;      // 1561
    dim3 grid(ngrp * 2);                    // x2 blocks: 8 nc / 4 waves
    wos_kernel<<<grid, 256, 0, stream>>>(x, weight, bias, mask, out);
}